// Round 5
// baseline (52.983 us; speedup 1.0000x reference)
//
#include <hip/hip_runtime.h>
#include <math.h>

#define TT 4096
#define DD 1024
#define NSPAN 8192
#define MW 30
#define WEMB 20
#define VECW (4*DD + WEMB)   // 4116 floats per span row

typedef float nf4 __attribute__((ext_vector_type(4)));  // native vec for nontemporal

// ---- kernel 1: fused {token_attn} + {counting-sort by b} in one launch ----
// block 0            : hist + scan + scatter (all in LDS, 1024 threads)
// blocks 1..TT/4     : token_attn for 4 tokens each (4 x 256-lane float4 dot)
__global__ void __launch_bounds__(1024) prep_kernel(
        const float* __restrict__ x,
        const float* __restrict__ attn_w,
        const float* __restrict__ attn_b,
        const int* __restrict__ bptr,
        float* __restrict__ ta,
        int* __restrict__ perm) {
    const int tid = threadIdx.x;
    if (blockIdx.x == 0) {
        __shared__ int h[TT];          // histogram, then running offsets
        __shared__ int wsum[16];
        #pragma unroll
        for (int k = 0; k < 4; ++k) h[tid * 4 + k] = 0;
        __syncthreads();
        #pragma unroll
        for (int k = 0; k < NSPAN / 1024; ++k)
            atomicAdd(&h[bptr[k * 1024 + tid]], 1);
        __syncthreads();
        const int v0 = h[tid*4+0], v1 = h[tid*4+1], v2 = h[tid*4+2], v3 = h[tid*4+3];
        const int s = v0 + v1 + v2 + v3;
        // inclusive wave scan over per-thread sums
        const int lane = tid & 63;
        int incl = s;
        #pragma unroll
        for (int off = 1; off < 64; off <<= 1) {
            int t = __shfl_up(incl, off);
            if (lane >= off) incl += t;
        }
        if (lane == 63) wsum[tid >> 6] = incl;
        __syncthreads();
        if (tid < 16) {   // scan the 16 wave totals within wave 0
            int ws = wsum[tid];
            #pragma unroll
            for (int off = 1; off < 16; off <<= 1) {
                int t = __shfl_up(ws, off);
                if (tid >= off) ws += t;
            }
            wsum[tid] = ws;
        }
        __syncthreads();
        const int waveoff = (tid >> 6) == 0 ? 0 : wsum[(tid >> 6) - 1];
        int excl = waveoff + (incl - s);
        h[tid*4+0] = excl;  excl += v0;
        h[tid*4+1] = excl;  excl += v1;
        h[tid*4+2] = excl;  excl += v2;
        h[tid*4+3] = excl;
        __syncthreads();
        // scatter via LDS atomics
        #pragma unroll
        for (int k = 0; k < NSPAN / 1024; ++k) {
            const int n = k * 1024 + tid;
            const int pos = atomicAdd(&h[bptr[n]], 1);
            perm[pos] = n;
        }
    } else {
        const int sub = tid >> 8;          // 0..3: which of 4 tokens
        const int l   = tid & 255;         // 0..255: float4 lane
        const int t   = (blockIdx.x - 1) * 4 + sub;
        const float4 v = ((const float4*)(x + (size_t)t * DD))[l];
        const float4 w = ((const float4*)attn_w)[l];
        float s = v.x * w.x + v.y * w.y + v.z * w.z + v.w * w.w;
        #pragma unroll
        for (int off = 32; off > 0; off >>= 1) s += __shfl_down(s, off);
        __shared__ float part[16];
        if ((tid & 63) == 0) part[tid >> 6] = s;   // wave id = 4*sub + (l>>6)
        __syncthreads();
        if (l == 0)
            ta[t] = part[sub*4] + part[sub*4+1] + part[sub*4+2] + part[sub*4+3]
                  + attn_b[0];
    }
}

// ---- kernel 2: one block per (sorted) span ----
__global__ void span_kernel(const float* __restrict__ x,
                            const int* __restrict__ bptr,
                            const int* __restrict__ eptr,
                            const float* __restrict__ embed_w,
                            const float* __restrict__ ta,
                            const int* __restrict__ perm,
                            float* __restrict__ out) {
    // XCD-chunked swizzle: block i -> sorted position (i%8)*1024 + i/8,
    // so each XCD's resident blocks cover a tight, contiguous token window.
    const int spos = (blockIdx.x & 7) * (NSPAN / 8) + (blockIdx.x >> 3);
    const int n    = perm[spos];
    const int tid  = threadIdx.x;          // 256 threads, one float4 of D each
    const int b     = bptr[n];
    const int e_raw = eptr[n];
    const int e     = min(e_raw, TT - 1);
    const int width = e_raw - b;
    const int len   = e - b + 1;           // <= MW

    const float4* xrow = (const float4*)(x + (size_t)b * DD);
    float* orow = out + (size_t)n * VECW;

    // issue row-b load FIRST: its latency hides under the softmax reduce
    float4 v = xrow[tid];

    // softmax over token_attn[b..e], wave 0 only
    __shared__ float wsm[32];
    if (tid < 64) {
        float tv = (tid < len) ? ta[b + tid] : -INFINITY;
        float m = tv;
        #pragma unroll
        for (int off = 32; off > 0; off >>= 1) m = fmaxf(m, __shfl_down(m, off));
        m = __shfl(m, 0);
        float ex = (tid < len) ? expf(tv - m) : 0.0f;
        float s = ex;
        #pragma unroll
        for (int off = 32; off > 0; off >>= 1) s += __shfl_down(s, off);
        s = __shfl(s, 0);
        if (tid < len) wsm[tid] = ex / s;
    }
    __syncthreads();

    {
        nf4 nv = { v.x, v.y, v.z, v.w };
        __builtin_nontemporal_store(nv, (nf4*)(orow) + tid);                // b_vec
    }
    // small stores early (out of the epilogue): width_emb + width scalar
    if (tid < WEMB)
        __builtin_nontemporal_store(embed_w[width * WEMB + tid], orow + 2*DD + tid);
    if (tid == 0)
        __builtin_nontemporal_store((float)width, out + (size_t)NSPAN * VECW + n);

    float w0 = wsm[0];
    float4 acc_h = make_float4(w0 * v.x, w0 * v.y, w0 * v.z, w0 * v.w);
    float4 acc_a = v;
    // pipeline: load row i while row i-1 accumulates; e_vec comes from last.
    for (int i = 1; i < len; ++i) {
        const float4 nv = xrow[(size_t)i * 256 + tid];
        const float w = wsm[i];
        acc_h.x += w * nv.x; acc_h.y += w * nv.y; acc_h.z += w * nv.z; acc_h.w += w * nv.w;
        acc_a.x += nv.x;     acc_a.y += nv.y;     acc_a.z += nv.z;     acc_a.w += nv.w;
        v = nv;
    }
    {
        nf4 nv = { v.x, v.y, v.z, v.w };
        __builtin_nontemporal_store(nv, (nf4*)(orow + DD) + tid);           // e_vec
    }
    const float inv = 1.0f / (float)len;
    acc_a.x *= inv; acc_a.y *= inv; acc_a.z *= inv; acc_a.w *= inv;
    nf4 nh = { acc_h.x, acc_h.y, acc_h.z, acc_h.w };
    nf4 na = { acc_a.x, acc_a.y, acc_a.z, acc_a.w };
    __builtin_nontemporal_store(nh, (nf4*)(orow + 2*DD + WEMB) + tid);      // head_emb
    __builtin_nontemporal_store(na, (nf4*)(orow + 3*DD + WEMB) + tid);      // span_avg
}

extern "C" void kernel_launch(void* const* d_in, const int* in_sizes, int n_in,
                              void* d_out, int out_size, void* d_ws, size_t ws_size,
                              hipStream_t stream) {
    const float* x       = (const float*)d_in[0];  // [1,T,D]
    const int*   b       = (const int*)  d_in[1];  // [1,N]
    const int*   e       = (const int*)  d_in[2];  // [1,N]
    const float* embed_w = (const float*)d_in[4];  // [MW,WEMB]
    const float* attn_w  = (const float*)d_in[5];  // [D,1]
    const float* attn_b  = (const float*)d_in[6];  // [1]
    float* out = (float*)d_out;

    // workspace layout
    float* ta   = (float*)d_ws;                    // TT floats
    int*   perm = (int*)(ta + TT);                 // NSPAN ints

    prep_kernel<<<1 + TT/4, 1024, 0, stream>>>(x, attn_w, attn_b, b, ta, perm);
    span_kernel<<<NSPAN, 256, 0, stream>>>(x, b, e, embed_w, ta, perm, out);
}

// Round 6
// 48.628 us; speedup vs baseline: 1.0896x; 1.0896x over previous
//
#include <hip/hip_runtime.h>
#include <math.h>

#define TT 4096
#define DD 1024
#define NSPAN 8192
#define MW 30
#define WEMB 20
#define VECW (4*DD + WEMB)   // 4116 floats per span row

typedef float nf4 __attribute__((ext_vector_type(4)));  // native vec for nontemporal

// ---- kernel 1: fused {token_attn} + {counting-sort by b} in one launch ----
// block 0            : hist + scan + scatter (all in LDS, 1024 threads)
// blocks 1..TT/4     : token_attn for 4 tokens each (4 x 256-lane float4 dot)
__global__ void __launch_bounds__(1024) prep_kernel(
        const float* __restrict__ x,
        const float* __restrict__ attn_w,
        const float* __restrict__ attn_b,
        const int* __restrict__ bptr,
        float* __restrict__ ta,
        int* __restrict__ perm) {
    const int tid = threadIdx.x;
    if (blockIdx.x == 0) {
        __shared__ int h[TT];          // histogram, then running offsets
        __shared__ int wsum[16];
        #pragma unroll
        for (int k = 0; k < 4; ++k) h[tid * 4 + k] = 0;
        __syncthreads();
        #pragma unroll
        for (int k = 0; k < NSPAN / 1024; ++k)
            atomicAdd(&h[bptr[k * 1024 + tid]], 1);
        __syncthreads();
        const int v0 = h[tid*4+0], v1 = h[tid*4+1], v2 = h[tid*4+2], v3 = h[tid*4+3];
        const int s = v0 + v1 + v2 + v3;
        // inclusive wave scan over per-thread sums
        const int lane = tid & 63;
        int incl = s;
        #pragma unroll
        for (int off = 1; off < 64; off <<= 1) {
            int t = __shfl_up(incl, off);
            if (lane >= off) incl += t;
        }
        if (lane == 63) wsum[tid >> 6] = incl;
        __syncthreads();
        if (tid < 16) {   // scan the 16 wave totals within wave 0
            int ws = wsum[tid];
            #pragma unroll
            for (int off = 1; off < 16; off <<= 1) {
                int t = __shfl_up(ws, off);
                if (tid >= off) ws += t;
            }
            wsum[tid] = ws;
        }
        __syncthreads();
        const int waveoff = (tid >> 6) == 0 ? 0 : wsum[(tid >> 6) - 1];
        int excl = waveoff + (incl - s);
        h[tid*4+0] = excl;  excl += v0;
        h[tid*4+1] = excl;  excl += v1;
        h[tid*4+2] = excl;  excl += v2;
        h[tid*4+3] = excl;
        __syncthreads();
        // scatter via LDS atomics
        #pragma unroll
        for (int k = 0; k < NSPAN / 1024; ++k) {
            const int n = k * 1024 + tid;
            const int pos = atomicAdd(&h[bptr[n]], 1);
            perm[pos] = n;
        }
    } else {
        const int sub = tid >> 8;          // 0..3: which of 4 tokens
        const int l   = tid & 255;         // 0..255: float4 lane
        const int t   = (blockIdx.x - 1) * 4 + sub;
        const float4 v = ((const float4*)(x + (size_t)t * DD))[l];
        const float4 w = ((const float4*)attn_w)[l];
        float s = v.x * w.x + v.y * w.y + v.z * w.z + v.w * w.w;
        #pragma unroll
        for (int off = 32; off > 0; off >>= 1) s += __shfl_down(s, off);
        __shared__ float part[16];
        if ((tid & 63) == 0) part[tid >> 6] = s;   // wave id = 4*sub + (l>>6)
        __syncthreads();
        if (l == 0)
            ta[t] = part[sub*4] + part[sub*4+1] + part[sub*4+2] + part[sub*4+3]
                  + attn_b[0];
    }
}

// ---- kernel 2: one block per (sorted) span ----
__global__ void span_kernel(const float* __restrict__ x,
                            const int* __restrict__ bptr,
                            const int* __restrict__ eptr,
                            const float* __restrict__ embed_w,
                            const float* __restrict__ ta,
                            const int* __restrict__ perm,
                            float* __restrict__ out) {
    // XCD-chunked swizzle: block i -> sorted position (i%8)*1024 + i/8,
    // so each XCD's resident blocks cover a tight, contiguous token window.
    const int spos = (blockIdx.x & 7) * (NSPAN / 8) + (blockIdx.x >> 3);
    const int n    = perm[spos];
    const int tid  = threadIdx.x;          // 256 threads, one float4 of D each
    const int b     = bptr[n];
    const int e_raw = eptr[n];
    const int e     = min(e_raw, TT - 1);
    const int width = e_raw - b;
    const int len   = e - b + 1;           // <= MW

    // softmax over token_attn[b..e], wave 0 only
    __shared__ float wsm[32];
    if (tid < 64) {
        float v = (tid < len) ? ta[b + tid] : -INFINITY;
        float m = v;
        #pragma unroll
        for (int off = 32; off > 0; off >>= 1) m = fmaxf(m, __shfl_down(m, off));
        m = __shfl(m, 0);
        float ex = (tid < len) ? expf(v - m) : 0.0f;
        float s = ex;
        #pragma unroll
        for (int off = 32; off > 0; off >>= 1) s += __shfl_down(s, off);
        s = __shfl(s, 0);
        if (tid < len) wsm[tid] = ex / s;
    }
    __syncthreads();

    float* orow = out + (size_t)n * VECW;
    const float4* xrow = (const float4*)(x + (size_t)b * DD);

    // pipeline: v holds row b+i; store b_vec immediately, e_vec from last.
    float4 v = xrow[tid];
    {
        nf4 nv = { v.x, v.y, v.z, v.w };
        __builtin_nontemporal_store(nv, (nf4*)(orow) + tid);                // b_vec
    }
    float w0 = wsm[0];
    float4 acc_h = make_float4(w0 * v.x, w0 * v.y, w0 * v.z, w0 * v.w);
    float4 acc_a = v;
    for (int i = 1; i < len; ++i) {
        const float4 nv = xrow[(size_t)i * 256 + tid];
        const float w = wsm[i];
        acc_h.x += w * nv.x; acc_h.y += w * nv.y; acc_h.z += w * nv.z; acc_h.w += w * nv.w;
        acc_a.x += nv.x;     acc_a.y += nv.y;     acc_a.z += nv.z;     acc_a.w += nv.w;
        v = nv;
    }
    {
        nf4 nv = { v.x, v.y, v.z, v.w };
        __builtin_nontemporal_store(nv, (nf4*)(orow + DD) + tid);           // e_vec
    }
    const float inv = 1.0f / (float)len;
    acc_a.x *= inv; acc_a.y *= inv; acc_a.z *= inv; acc_a.w *= inv;
    nf4 nh = { acc_h.x, acc_h.y, acc_h.z, acc_h.w };
    nf4 na = { acc_a.x, acc_a.y, acc_a.z, acc_a.w };
    __builtin_nontemporal_store(nh, (nf4*)(orow + 2*DD + WEMB) + tid);      // head_emb
    __builtin_nontemporal_store(na, (nf4*)(orow + 3*DD + WEMB) + tid);      // span_avg

    if (tid < WEMB)
        __builtin_nontemporal_store(embed_w[width * WEMB + tid], orow + 2*DD + tid);
    if (tid == 0)
        __builtin_nontemporal_store((float)width, out + (size_t)NSPAN * VECW + n);
}

extern "C" void kernel_launch(void* const* d_in, const int* in_sizes, int n_in,
                              void* d_out, int out_size, void* d_ws, size_t ws_size,
                              hipStream_t stream) {
    const float* x       = (const float*)d_in[0];  // [1,T,D]
    const int*   b       = (const int*)  d_in[1];  // [1,N]
    const int*   e       = (const int*)  d_in[2];  // [1,N]
    const float* embed_w = (const float*)d_in[4];  // [MW,WEMB]
    const float* attn_w  = (const float*)d_in[5];  // [D,1]
    const float* attn_b  = (const float*)d_in[6];  // [1]
    float* out = (float*)d_out;

    // workspace layout
    float* ta   = (float*)d_ws;                    // TT floats
    int*   perm = (int*)(ta + TT);                 // NSPAN ints

    prep_kernel<<<1 + TT/4, 1024, 0, stream>>>(x, attn_w, attn_b, b, ta, perm);
    span_kernel<<<NSPAN, 256, 0, stream>>>(x, b, e, embed_w, ta, perm, out);
}